// Round 5
// baseline (225.256 us; speedup 1.0000x reference)
//
#include <hip/hip_runtime.h>
#include <hip/hip_bf16.h>
#include <cstdint>

// Problem constants (reference: N=16384, F=1024, H=256)
#define NR 16384
#define NF 1024
#define NH 256

typedef __bf16 bf16x8 __attribute__((ext_vector_type(8)));
typedef float f32x4 __attribute__((ext_vector_type(4)));
typedef unsigned short us8 __attribute__((ext_vector_type(8)));

static __device__ __forceinline__ unsigned short f2bf(float f) {
    unsigned u = __float_as_uint(f);
    u += 0x7FFFu + ((u >> 16) & 1u);   // RNE
    return (unsigned short)(u >> 16);
}
static __device__ __forceinline__ unsigned cvt2(float a, float b) {
    return ((unsigned)f2bf(b) << 16) | (unsigned)f2bf(a);
}

// async global->LDS, 16 B per lane; LDS dest is HW-forced to base + lane*16,
// so all source-side swizzles are applied to the GLOBAL address, never LDS.
__device__ __forceinline__ void gl2lds16(const void* gp, void* lp) {
    __builtin_amdgcn_global_load_lds(
        (const __attribute__((address_space(1))) unsigned int*)gp,
        (__attribute__((address_space(3))) unsigned int*)lp, 16, 0, 0);
}

// ---------------------------------------------------------------------------
// LDS-tiled transpose+convert: dst_bf16[C][R] = src_f32[R][C]^T
// ---------------------------------------------------------------------------
__global__ __launch_bounds__(256) void transpose_bf_kernel(
    const float* __restrict__ src, unsigned short* __restrict__ dst, int R, int C) {
    __shared__ float tile[32][33];
    const int c0 = blockIdx.x * 32, r0 = blockIdx.y * 32;
    const int t = threadIdx.x;
#pragma unroll
    for (int p = 0; p < 4; p++) {
        int idx = t + 256 * p;
        int r = idx >> 5, c = idx & 31;
        tile[r][c] = src[(size_t)(r0 + r) * C + c0 + c];
    }
    __syncthreads();
#pragma unroll
    for (int p = 0; p < 4; p++) {
        int idx = t + 256 * p;
        int rr = idx & 31, cc = idx >> 5;
        dst[(size_t)(c0 + cc) * R + r0 + rr] = f2bf(tile[rr][cc]);
    }
}

// ---------------------------------------------------------------------------
// FUSED: per 32-row m-strip:
//   phase 1: g = X @ We + be (N=256 full, BK=32 dbuf), critic c fused
//   g -> swizzled LDS tile (never global)
//   phase 2: rec = g @ Wd + bd against WdT chunks; MSE sum vs X (L3 re-read)
// ---------------------------------------------------------------------------
__global__ __launch_bounds__(256) void fused_kernel(
    const float* __restrict__ X, const unsigned short* __restrict__ WeT,
    const unsigned short* __restrict__ WdT,
    const float* __restrict__ be, const float* __restrict__ bd,
    const float* __restrict__ Wc,
    float* __restrict__ cpart, float* __restrict__ mseparts) {
    __shared__ union {
        struct { float As[2][32 * 32]; unsigned short Bs[2][256 * 32]; } p1;          // 8+32 KB
        struct { unsigned short gs[32 * 256]; unsigned short Bs2[2][128 * 32]; } p2;  // 16+16 KB
    } sh;
    __shared__ float credu[4][32];
    __shared__ float msred[4];
    const int t = threadIdx.x;
    const int m0 = blockIdx.x * 32;
    const int w = t >> 6, lane = t & 63, q = lane >> 4, li = lane & 15;
    const int nw = w * 64;

    // ---------------- phase 1: X @ We ----------------
    const int ar = t >> 3, acx = (t & 7) ^ (ar & 7);        // A: fp32, 8 slots/row
    const float* Ag = X + (size_t)(m0 + ar) * NF + acx * 4;
    const int br = t >> 2, bcx = (t & 3) ^ ((br >> 1) & 3); // B: bf16, 4 slots/row
    const unsigned short* Bg = WeT + (size_t)br * NF + bcx * 8;

    f32x4 acc[2][4] = {};
    gl2lds16(Ag, &sh.p1.As[0][t * 4]);
#pragma unroll
    for (int p = 0; p < 4; p++)
        gl2lds16(Bg + (size_t)(64 * p) * NF, &sh.p1.Bs[0][(t + 256 * p) * 8]);

    for (int it = 0; it < 32; ++it) {
        const int cur = it & 1;
        __syncthreads();
        if (it + 1 < 32) {
            const int k1 = (it + 1) * 32;
            gl2lds16(Ag + k1, &sh.p1.As[cur ^ 1][t * 4]);
#pragma unroll
            for (int p = 0; p < 4; p++)
                gl2lds16(Bg + (size_t)(64 * p) * NF + k1, &sh.p1.Bs[cur ^ 1][(t + 256 * p) * 8]);
        }
        bf16x8 af[2], bfv[4];
#pragma unroll
        for (int i = 0; i < 2; i++) {
            int r = i * 16 + li;
            int s0 = (2 * q) ^ (r & 7);
            f32x4 lo = *(const f32x4*)&sh.p1.As[cur][r * 32 + s0 * 4];
            f32x4 hi = *(const f32x4*)&sh.p1.As[cur][r * 32 + (s0 ^ 1) * 4];
            uint4 pk;
            pk.x = cvt2(lo[0], lo[1]); pk.y = cvt2(lo[2], lo[3]);
            pk.z = cvt2(hi[0], hi[1]); pk.w = cvt2(hi[2], hi[3]);
            af[i] = __builtin_bit_cast(bf16x8, pk);
        }
#pragma unroll
        for (int j = 0; j < 4; j++) {
            int r = nw + j * 16 + li;
            int s = q ^ ((r >> 1) & 3);
            bfv[j] = __builtin_bit_cast(bf16x8, *(const us8*)&sh.p1.Bs[cur][r * 32 + s * 8]);
        }
#pragma unroll
        for (int i = 0; i < 2; i++)
#pragma unroll
            for (int j = 0; j < 4; j++)
                acc[i][j] = __builtin_amdgcn_mfma_f32_16x16x32_bf16(bfv[j], af[i], acc[i][j], 0, 0, 0);
    }
    __syncthreads();   // all p1 LDS reads done; p2 region now writable

    // phase-2 staging addresses (swizzle on global k-slot; LDS stays lane-linear)
    const int rB = t >> 2;
    const int sB = (t & 3) ^ (rB & 3) ^ ((rB >> 2) & 3);
    const unsigned short* Wg  = WdT + (size_t)rB * NH + sB * 8;
    const unsigned short* Wg2 = WdT + (size_t)(rB + 64) * NH + sB * 8;
    // prefetch first Wd chunk (nc=0, kc=0) while epilogue computes
    gl2lds16(Wg,  &sh.p2.Bs2[0][t * 8]);
    gl2lds16(Wg2, &sh.p2.Bs2[0][(t + 256) * 8]);

    // phase-1 epilogue: g -> swizzled LDS tile + fused critic
#pragma unroll
    for (int i = 0; i < 2; i++) {
        float csum = 0.f;
        const int m = i * 16 + li;
#pragma unroll
        for (int j = 0; j < 4; j++) {
            int colb = nw + j * 16 + q * 4;
            float4 be4 = *(const float4*)&be[colb];
            float4 wc4 = *(const float4*)&Wc[colb];
            float v0 = acc[i][j][0] + be4.x;
            float v1 = acc[i][j][1] + be4.y;
            float v2 = acc[i][j][2] + be4.z;
            float v3 = acc[i][j][3] + be4.w;
            csum += v0 * wc4.x + v1 * wc4.y + v2 * wc4.z + v3 * wc4.w;
            ushort4 st = { f2bf(v0), f2bf(v1), f2bf(v2), f2bf(v3) };
            // unswizzled slot = colb>>3; physical slot = slot ^ m; 8-B half by q&1
            int sl = ((colb >> 3) ^ m);
            *(ushort4*)&sh.p2.gs[m * 256 + sl * 8 + (q & 1) * 4] = st;
        }
        csum += __shfl_down(csum, 32);
        csum += __shfl_down(csum, 16);
        if (lane < 16) credu[w][i * 16 + lane] = csum;
    }
    __syncthreads();   // gs ready, Bs2[0] drained, credu ready
    if (t < 32)
        cpart[m0 + t] = credu[0][t] + credu[1][t] + credu[2][t] + credu[3][t];

    // ---------------- phase 2: g @ Wd + MSE ----------------
    float lsum = 0.f;
    f32x4 acc2[2][2] = {};
    for (int it = 0; it < 64; ++it) {
        const int nc = it >> 3, kc = it & 7, cur = it & 1;
        if (it) __syncthreads();
        if (it + 1 < 64) {
            const int nc1 = (it + 1) >> 3, kc1 = (it + 1) & 7;
            const size_t off = (size_t)(nc1 * 128) * NH + kc1 * 32;
            gl2lds16(Wg + off,  &sh.p2.Bs2[cur ^ 1][t * 8]);
            gl2lds16(Wg2 + off, &sh.p2.Bs2[cur ^ 1][(t + 256) * 8]);
        }
        bf16x8 af[2], bfv[2];
#pragma unroll
        for (int i = 0; i < 2; i++) {
            int m = i * 16 + li;
            int sl = (kc * 4 + q) ^ m;
            af[i] = __builtin_bit_cast(bf16x8, *(const us8*)&sh.p2.gs[m * 256 + sl * 8]);
        }
#pragma unroll
        for (int j = 0; j < 2; j++) {
            int r = w * 32 + j * 16 + li;
            int s = q ^ (r & 3) ^ ((r >> 2) & 3);
            bfv[j] = __builtin_bit_cast(bf16x8, *(const us8*)&sh.p2.Bs2[cur][r * 32 + s * 8]);
        }
#pragma unroll
        for (int i = 0; i < 2; i++)
#pragma unroll
            for (int j = 0; j < 2; j++)
                acc2[i][j] = __builtin_amdgcn_mfma_f32_16x16x32_bf16(bfv[j], af[i], acc2[i][j], 0, 0, 0);
        if (kc == 7) {
            // per-n-chunk epilogue: rec vs X (L3-resident re-read)
#pragma unroll
            for (int i = 0; i < 2; i++) {
                const size_t rowoff = (size_t)(m0 + i * 16 + li) * NF;
#pragma unroll
                for (int j = 0; j < 2; j++) {
                    int colb = nc * 128 + w * 32 + j * 16 + q * 4;
                    float4 bd4 = *(const float4*)&bd[colb];
                    float4 xr  = *(const float4*)&X[rowoff + colb];
                    float d0 = acc2[i][j][0] + bd4.x - xr.x;
                    float d1 = acc2[i][j][1] + bd4.y - xr.y;
                    float d2 = acc2[i][j][2] + bd4.z - xr.z;
                    float d3 = acc2[i][j][3] + bd4.w - xr.w;
                    lsum += d0 * d0 + d1 * d1 + d2 * d2 + d3 * d3;
                    acc2[i][j] = (f32x4){0.f, 0.f, 0.f, 0.f};
                }
            }
        }
    }
#pragma unroll
    for (int o = 32; o; o >>= 1) lsum += __shfl_down(lsum, o);
    if (lane == 0) msred[w] = lsum;
    __syncthreads();
    if (t == 0)
        atomicAdd(&mseparts[blockIdx.x & 63], msred[0] + msred[1] + msred[2] + msred[3]);
}

// ---------------------------------------------------------------------------
// compaction: cP = c[s==p], cR = c[s!=p] (order-free), wave-aggregated atomics
// ---------------------------------------------------------------------------
__global__ __launch_bounds__(256) void compact_kernel(
    const float* __restrict__ c, const int* __restrict__ s, const int* __restrict__ pv,
    float* __restrict__ cP, float* __restrict__ cR, int* __restrict__ cnt) {
    int i = blockIdx.x * 256 + threadIdx.x;
    float ci = c[i];
    bool pr = (s[i] == pv[0]);
    int lane = threadIdx.x & 63;
    unsigned long long m = __ballot(pr);
    {
        int cm = __popcll(m);
        int base = 0;
        if (lane == 0 && cm) base = atomicAdd(&cnt[0], cm);
        base = __shfl(base, 0);
        int off = __popcll(m & ((1ull << lane) - 1ull));
        if (pr) cP[base + off] = ci;
    }
    {
        unsigned long long mm = ~m;
        int cm = __popcll(mm);
        int base = 0;
        if (lane == 0 && cm) base = atomicAdd(&cnt[1], cm);
        base = __shfl(base, 0);
        int off = __popcll(mm & ((1ull << lane) - 1ull));
        if (!pr) cR[base + off] = ci;
    }
}

// ---------------------------------------------------------------------------
// pairwise masked L1: sum_{a in P, b in R} |cP[a]-cR[b]| -> 64 partial cells
// ---------------------------------------------------------------------------
__global__ __launch_bounds__(256) void pair_kernel(
    const float* __restrict__ cP, const float* __restrict__ cR,
    const int* __restrict__ cnt, float* __restrict__ pairparts) {
    __shared__ float sj[1024];
    const int nP = cnt[0], nR = cnt[1];
    const int jb = blockIdx.x * 1024;
    int jn = nR - jb; if (jn < 0) jn = 0; if (jn > 1024) jn = 1024;
    for (int j = threadIdx.x; j < 1024; j += 256)
        sj[j] = (jb + j < nR) ? cR[jb + j] : 0.f;
    __syncthreads();
    const int a0 = blockIdx.y * 512 + threadIdx.x;
    const int a1 = a0 + 256;
    const float ca0 = (a0 < nP) ? cP[a0] : 0.f;
    const float ca1 = (a1 < nP) ? cP[a1] : 0.f;
    float s0 = 0.f, s1 = 0.f;
#pragma unroll 4
    for (int j4 = 0; j4 < 256; j4++) {
        float4 v = *(const float4*)&sj[j4 * 4];
        s0 += fabsf(ca0 - v.x) + fabsf(ca0 - v.y) + fabsf(ca0 - v.z) + fabsf(ca0 - v.w);
        s1 += fabsf(ca1 - v.x) + fabsf(ca1 - v.y) + fabsf(ca1 - v.z) + fabsf(ca1 - v.w);
    }
    float pad = (float)(1024 - jn);
    s0 -= pad * fabsf(ca0);
    s1 -= pad * fabsf(ca1);
    if (a0 >= nP) s0 = 0.f;
    if (a1 >= nP) s1 = 0.f;
    float s = s0 + s1;
#pragma unroll
    for (int o = 32; o; o >>= 1) s += __shfl_down(s, o);
    if ((threadIdx.x & 63) == 0)
        atomicAdd(&pairparts[((blockIdx.y << 4) ^ blockIdx.x ^ (threadIdx.x >> 6)) & 63], s);
}

// ---------------------------------------------------------------------------
__global__ void finalize_kernel(const float* __restrict__ mseparts,
                                const float* __restrict__ pairparts,
                                const int* __restrict__ cnt, float* __restrict__ out) {
    float ms = 0.f, ps = 0.f;
    for (int i = 0; i < 64; i++) { ms += mseparts[i]; ps += pairparts[i]; }
    out[0] = ms / (float)((size_t)NR * NF);
    out[1] = (float)NR;
    out[2] = ps / (float)cnt[0];
    out[3] = (float)cnt[0];
}

extern "C" void kernel_launch(void* const* d_in, const int* in_sizes, int n_in,
                              void* d_out, int out_size, void* d_ws, size_t ws_size,
                              hipStream_t stream) {
    const float* X  = (const float*)d_in[0];
    const float* We = (const float*)d_in[1];
    const float* be = (const float*)d_in[2];
    const float* Wd = (const float*)d_in[3];
    const float* bd = (const float*)d_in[4];
    const float* Wc = (const float*)d_in[5];
    // bc (d_in[6]) omitted: cancels in |c_i - c_j|
    const int*   s  = (const int*)d_in[7];
    const int*   pv = (const int*)d_in[8];

    char* ws = (char*)d_ws;
    float* mseparts  = (float*)(ws + 0);        // 64 f
    float* pairparts = (float*)(ws + 256);      // 64 f
    int*   cnt       = (int*)(ws + 512);        // 2 ints
    float* cpart     = (float*)(ws + 1024);     // 16384 f (plain stores, fully written)
    float* cP        = (float*)(ws + 1024 + 65536);
    float* cR        = (float*)(ws + 1024 + 2 * 65536);
    unsigned short* WeT = (unsigned short*)(ws + 1024 + 3 * 65536);  // [256][1024] bf16
    unsigned short* WdT = WeT + (size_t)NH * NF;                     // [1024][256] bf16

    (void)hipMemsetAsync(d_ws, 0, 1024, stream);
    transpose_bf_kernel<<<dim3(8, 32), 256, 0, stream>>>(We, WeT, 1024, 256);
    transpose_bf_kernel<<<dim3(32, 8), 256, 0, stream>>>(Wd, WdT, 256, 1024);
    fused_kernel<<<512, 256, 0, stream>>>(X, WeT, WdT, be, bd, Wc, cpart, mseparts);
    compact_kernel<<<64, 256, 0, stream>>>(cpart, s, pv, cP, cR, cnt);
    pair_kernel<<<dim3(16, 32), 256, 0, stream>>>(cP, cR, cnt, pairparts);
    finalize_kernel<<<1, 1, 0, stream>>>(mseparts, pairparts, cnt, (float*)d_out);
}